// Round 1
// baseline (237.831 us; speedup 1.0000x reference)
//
#include <hip/hip_runtime.h>
#include <hip/hip_bf16.h>
#include <stdint.h>

// ---------------------------------------------------------------------------
// CustomConvLayer: out[b,o,h,w] = sum_{c,dh,dw} xpad[b,c,h+dh,w+dw] * W[o,c,dh*3+dw]
// Implicit-im2col GEMM: M = B*H*W (262144), N = O (128), K = 9*C (576), bf16 MFMA.
// kk ordering: kk = tap*64 + c  (tap = dh*3+dw)
// ---------------------------------------------------------------------------

typedef __bf16 bf16x8 __attribute__((ext_vector_type(8)));
typedef float  f32x4  __attribute__((ext_vector_type(4)));

#define GLD_TO_LDS16(g, l)                                                        \
  __builtin_amdgcn_global_load_lds((const __attribute__((address_space(1))) void*)(g), \
                                   (__attribute__((address_space(3))) void*)(l), 16, 0, 0)

// ---------------- prepass: x NCHW fp32 -> padded NHWC bf16 -------------------
// xpad[b][hp][wp][c], hp,wp in [0,130), interior hp=h+1, wp=w+1
__global__ __launch_bounds__(256) void xform_x(const float* __restrict__ x,
                                               __bf16* __restrict__ xpad) {
  __shared__ float tile[64][129];  // +1 pad: write-phase reads column-wise
  const int tid = threadIdx.x;
  const int b = blockIdx.x >> 7;
  const int h = blockIdx.x & 127;
  const float* src = x + (((size_t)b * 64) * 128 + h) * 128;  // + c*128*128 + w
  for (int i = tid; i < 64 * 128; i += 256) {
    const int c = i >> 7, w = i & 127;
    tile[c][w] = src[(size_t)c * 128 * 128 + w];
  }
  __syncthreads();
  __bf16* dst = xpad + ((size_t)(b * 130 + h + 1) * 130 + 1) * 64;
  for (int i = tid; i < 128 * 64; i += 256) {
    const int w = i >> 6, c = i & 63;
    dst[(size_t)w * 64 + c] = (__bf16)tile[c][w];
  }
}

// ---------------- prepass: weights [O][C][9] fp32 -> Bt[o][tap*64+c] bf16 ----
__global__ __launch_bounds__(256) void xform_w(const float* __restrict__ wgt,
                                               __bf16* __restrict__ Bt) {
  const int i = blockIdx.x * 256 + threadIdx.x;
  if (i >= 128 * 576) return;
  const int o = i / 576;
  const int r = i - o * 576;
  const int tap = r >> 6;
  const int c = r & 63;
  Bt[i] = (__bf16)wgt[(o * 64 + c) * 9 + tap];
}

// ---------------- main GEMM: one block per (b,h); M-tile=128(w), N-tile=128 --
__global__ __launch_bounds__(256) void conv_mfma(const __bf16* __restrict__ xpad,
                                                 const __bf16* __restrict__ Bt,
                                                 float* __restrict__ out) {
  __shared__ alignas(16) __bf16 Alds[128 * 32];  // [row=w][32 k] 64B rows, XOR-swizzled 16B chunks
  __shared__ alignas(16) __bf16 Blds[128 * 32];  // [row=n][32 k] same layout
  const int tid  = threadIdx.x;
  const int lane = tid & 63;
  const int wave = tid >> 6;
  const int quad = lane >> 4;
  const int l16  = lane & 15;
  const int b  = blockIdx.x >> 7;
  const int h  = blockIdx.x & 127;
  const int wm = wave >> 1;  // M half (0..1)
  const int wn = wave & 1;   // N half (0..1)

  f32x4 acc[4][4] = {};

  for (int s = 0; s < 18; ++s) {
    const int tap = s >> 1;
    const int c0  = (s & 1) << 5;
    const int dh  = tap / 3;
    const int dw  = tap % 3;
    // A tile: rows m=w 0..127, k = c0..c0+31 of this tap -> contiguous NHWC slab
    const __bf16* Abase = xpad + (((size_t)(b * 130 + h + dh) * 130 + dw) << 6) + c0;
    const __bf16* Bbase = Bt + (s << 5);  // + n*576 per row

    __syncthreads();  // protect LDS from previous iteration's readers
#pragma unroll
    for (int r = 0; r < 2; ++r) {
      const int ch  = tid + (r << 8);        // 16B chunk id, 512 total per matrix
      const int row = ch >> 2;               // 4 chunks per 64B row
      const int qp  = ch & 3;                // LDS chunk slot
      const int qa  = qp ^ ((row >> 1) & 3); // XOR swizzle: which global chunk lands here
      const __bf16* ga = Abase + (row << 6) + (qa << 3);
      const __bf16* gb = Bbase + row * 576 + (qa << 3);
      char* la = (char*)Alds + (wave << 10) + (r << 12);  // wave-uniform LDS base
      char* lb = (char*)Blds + (wave << 10) + (r << 12);
      GLD_TO_LDS16(ga, la);
      GLD_TO_LDS16(gb, lb);
    }
    __syncthreads();  // drains vmcnt (compiler emits waitcnt before s_barrier)

    bf16x8 aF[4], bF[4];
#pragma unroll
    for (int i = 0; i < 4; ++i) {
      const int ra = (wm << 6) + (i << 4) + l16;   // A row = m
      const int qa = quad ^ ((ra >> 1) & 3);
      aF[i] = *(const bf16x8*)(Alds + (ra << 5) + (qa << 3));
      const int rb = (wn << 6) + (i << 4) + l16;   // B row = n
      const int qb = quad ^ ((rb >> 1) & 3);
      bF[i] = *(const bf16x8*)(Blds + (rb << 5) + (qb << 3));
    }
#pragma unroll
    for (int i = 0; i < 4; ++i)
#pragma unroll
      for (int j = 0; j < 4; ++j)
        acc[i][j] = __builtin_amdgcn_mfma_f32_16x16x32_bf16(aF[i], bF[j], acc[i][j], 0, 0, 0);
  }

  // epilogue: D col = lane&15 = n (out channel), rows = quad*4+reg = m (w)
#pragma unroll
  for (int j = 0; j < 4; ++j) {
    const int n = (wn << 6) + (j << 4) + l16;
    float* orow = out + (((size_t)(b * 128 + n) * 128 + h) << 7);
#pragma unroll
    for (int i = 0; i < 4; ++i) {
      const int m0 = (wm << 6) + (i << 4) + (quad << 2);
      *(f32x4*)(orow + m0) = acc[i][j];  // 4 consecutive w, 16B aligned
    }
  }
}

// ---------------- fallback (if workspace too small): direct fp32 conv -------
__global__ void conv_naive(const float* __restrict__ x, const float* __restrict__ wgt,
                           float* __restrict__ out, int total) {
  int idx = blockIdx.x * 256 + threadIdx.x;
  if (idx >= total) return;
  const int w = idx & 127;
  const int h = (idx >> 7) & 127;
  const int o = (idx >> 14) & 127;
  const int b = idx >> 21;
  float s = 0.f;
  for (int c = 0; c < 64; ++c) {
    const float* xc = x + ((size_t)(b * 64 + c) * 128) * 128;
    const float* wc = wgt + (o * 64 + c) * 9;
    for (int dh = 0; dh < 3; ++dh) {
      const int hh = h + dh - 1;
      if (hh < 0 || hh >= 128) continue;
      for (int dw = 0; dw < 3; ++dw) {
        const int ww = w + dw - 1;
        if (ww < 0 || ww >= 128) continue;
        s += xc[hh * 128 + ww] * wc[dh * 3 + dw];
      }
    }
  }
  out[idx] = s;
}

extern "C" void kernel_launch(void* const* d_in, const int* in_sizes, int n_in,
                              void* d_out, int out_size, void* d_ws, size_t ws_size,
                              hipStream_t stream) {
  const float* x   = (const float*)d_in[0];
  const float* wgt = (const float*)d_in[1];
  float* out = (float*)d_out;

  const size_t BT_BYTES   = 128ull * 576 * sizeof(__bf16);            // 147456
  const size_t XPAD_BYTES = 16ull * 130 * 130 * 64 * sizeof(__bf16);  // 34.6 MB

  if (ws_size < BT_BYTES + XPAD_BYTES) {
    const int total = 16 * 128 * 128 * 128;
    conv_naive<<<(total + 255) / 256, 256, 0, stream>>>(x, wgt, out, total);
    return;
  }

  __bf16* Bt   = (__bf16*)d_ws;
  __bf16* xpad = (__bf16*)((char*)d_ws + BT_BYTES);

  hipMemsetAsync(xpad, 0, XPAD_BYTES, stream);  // zero padding border (and interior, overwritten)
  xform_w<<<(128 * 576 + 255) / 256, 256, 0, stream>>>(wgt, Bt);
  xform_x<<<16 * 128, 256, 0, stream>>>(x, xpad);
  conv_mfma<<<16 * 128, 256, 0, stream>>>(xpad, Bt, out);
}